// Round 20
// baseline (72.616 us; speedup 1.0000x reference)
//
#include <hip/hip_runtime.h>
#include <stdint.h>

// GPT2 attention fused pipeline, MI355X/gfx950.
// B=2, S=2048, H=768, nh=12, hd=64. fp32 I/O, bf16 internal compute (MFMA).
// R14: fragment-order 4KB K/V tiles. R15: merged q-pair sweep. R16: GEMM BK=64
// + XOR-swizzled LDS. R17: proj 64x128 tiles. R19: 1-deep attn staging.
// R20: attn __launch_bounds__(256,3) -> 12 waves/CU (TLP pays now that R14
// removed the TA bottleneck; VGPR capped ~168, live state ~160 should fit).

#define B_   2
#define S_   2048
#define H_   768
#define NH_  12
#define HD_  64
#define M_   4096      // B_*S_
#define K_   768
#define N_QKV 2304
#define QKV_ELEMS (B_*NH_*S_*HD_)   // per tensor (Q or Ktiles or Vtiles)
#define SCL_ 0.18033688f            // (1/sqrt(64)) * log2(e)

using bf16x8 = __attribute__((ext_vector_type(8))) __bf16;
using f32x4  = __attribute__((ext_vector_type(4))) float;
using f32x16 = __attribute__((ext_vector_type(16))) float;

__device__ inline unsigned short f2bf(float f) {
  unsigned int u = __float_as_uint(f);
  u = (u + 0x7FFFu + ((u >> 16) & 1u)) >> 16;   // RNE
  return (unsigned short)u;
}
__device__ inline float fexp2(float x) {        // v_exp_f32 = 2^x
  float r; asm("v_exp_f32 %0, %1" : "=v"(r) : "v"(x)); return r;
}
__device__ inline unsigned cvtpk(float lo, float hi) {
  unsigned r; asm("v_cvt_pk_bf16_f32 %0, %1, %2" : "=v"(r) : "v"(lo), "v"(hi)); return r;
}
// async global->LDS, 16B per lane; lds base wave-uniform; HW writes lane l at
// ldsbase + l*16. Fire-and-forget (R9/R10/R18 lessons).
__device__ inline void gload_lds16(const void* g, void* l) {
  __builtin_amdgcn_global_load_lds((const __attribute__((address_space(1))) void*)g,
                                   (__attribute__((address_space(3))) void*)l, 16, 0, 0);
}
#define VWAIT0() do { asm volatile("s_waitcnt vmcnt(0)" ::: "memory"); \
                      __builtin_amdgcn_sched_barrier(0); } while (0)
#define LWAIT0() do { asm volatile("s_waitcnt lgkmcnt(0)" ::: "memory"); \
                      __builtin_amdgcn_sched_barrier(0); } while (0)

// ---------------- cast fp32 -> bf16 (3 tensors in one launch) ----------------
__global__ void cast3(const float* __restrict__ s0, unsigned short* __restrict__ d0, int n0f,
                      const float* __restrict__ s1, unsigned short* __restrict__ d1, int n1f,
                      const float* __restrict__ s2, unsigned short* __restrict__ d2, int n2f) {
  int i = blockIdx.x * blockDim.x + threadIdx.x;
  const float* s; unsigned short* d; int j;
  if (i < n0f)                { s = s0; d = d0; j = i; }
  else if (i < n0f + n1f)     { s = s1; d = d1; j = i - n0f; }
  else if (i < n0f + n1f + n2f) { s = s2; d = d2; j = i - n0f - n1f; }
  else return;
  float4 v = reinterpret_cast<const float4*>(s)[j];
  ushort4 o;
  o.x = f2bf(v.x); o.y = f2bf(v.y); o.z = f2bf(v.z); o.w = f2bf(v.w);
  reinterpret_cast<ushort4*>(d)[j] = o;
}

// ---------------- NT GEMM: C[m,n] = sum_k A[m,k]*Bw[n,k] + bias[n] ----------------
// R16: BK=64 + XOR-swizzled LDS (linear dest, inverse-swizzled global source).
// R17: template TM (128 for QKV, 64 for proj -> 384 blocks).
// MODE 0 scatter: Q row-major; K/V fragment-order 4KB tiles (see R14).
// MODE 1: fp32 store to out.
template<int N, int MODE, int GX, int TM>
__global__ __launch_bounds__(256, 3)
void gemm_nt(const unsigned short* __restrict__ A,
             const unsigned short* __restrict__ Bw,
             const float* __restrict__ bias,
             unsigned short* __restrict__ qkv_base,
             float* __restrict__ outp)
{
  __shared__ unsigned short As[TM*64];
  __shared__ unsigned short Bs[128*64];
  const int tid  = threadIdx.x;
  const int lane = tid & 63;
  const int wid  = tid >> 6;
  const int g = lane >> 4, lr = lane & 15;
  const int wm = wid >> 1, wn = wid & 1;
  const int cpx = (GX * (M_/TM)) >> 3;
  const int id  = blockIdx.x;
  const int sw  = (id & 7) * cpx + (id >> 3);
  const int n0 = (sw % GX) * 128;
  const int m0 = (sw / GX) * TM;
  constexpr int NI = TM / 32;              // 16-row frags per wave (M dir)

  f32x4 acc[NI][4];
  #pragma unroll
  for (int i = 0; i < NI; ++i)
    #pragma unroll
    for (int j = 0; j < 4; ++j) acc[i][j] = f32x4{0.f, 0.f, 0.f, 0.f};

  for (int k0 = 0; k0 < K_; k0 += 64) {
    #pragma unroll
    for (int it = 0; it < TM/32; ++it) {   // A: TM*8 chunks
      int c = it*256 + wid*64 + lane;
      int row = c >> 3, seg = (c & 7) ^ (row & 7);
      int lb = __builtin_amdgcn_readfirstlane((it*256 + wid*64) * 8);
      gload_lds16(&A[(size_t)(m0 + row) * K_ + k0 + seg*8], &As[lb]);
    }
    #pragma unroll
    for (int it = 0; it < 4; ++it) {       // B: 1024 chunks
      int c = it*256 + wid*64 + lane;
      int row = c >> 3, seg = (c & 7) ^ (row & 7);
      int lb = __builtin_amdgcn_readfirstlane((it*256 + wid*64) * 8);
      gload_lds16(&Bw[(size_t)(n0 + row) * K_ + k0 + seg*8], &Bs[lb]);
    }
    __syncthreads();
    #pragma unroll
    for (int ks = 0; ks < 2; ++ks) {
      bf16x8 af[NI], bfr[4];
      #pragma unroll
      for (int i = 0; i < NI; ++i) {
        int ra = wm*(TM/2) + i*16 + lr;
        af[i]  = *reinterpret_cast<const bf16x8*>(&As[(ra*8 + ((ks*4+g) ^ (ra&7)))*8]);
      }
      #pragma unroll
      for (int j = 0; j < 4; ++j) {
        int rb = wn*64 + j*16 + lr;
        bfr[j] = *reinterpret_cast<const bf16x8*>(&Bs[(rb*8 + ((ks*4+g) ^ (rb&7)))*8]);
      }
      #pragma unroll
      for (int i = 0; i < NI; ++i)
        #pragma unroll
        for (int j = 0; j < 4; ++j)
          acc[i][j] = __builtin_amdgcn_mfma_f32_16x16x32_bf16(af[i], bfr[j], acc[i][j], 0, 0, 0);
    }
    __syncthreads();
  }

  // epilogue: C row = m0+wm*(TM/2)+i*16+g*4+r, col = n0+wn*64+j*16+lr
  #pragma unroll
  for (int j = 0; j < 4; ++j) {
    int col = n0 + wn*64 + j*16 + lr;
    float bv = bias[col];
    if constexpr (MODE == 0) {
      int which = col / 768;               // 0=Q 1=K 2=V
      int rem = col - which * 768;
      int h = rem >> 6, d = rem & 63;
      if (which == 0) {
        unsigned short* dst = qkv_base;
        #pragma unroll
        for (int i = 0; i < NI; ++i)
          #pragma unroll
          for (int r = 0; r < 4; ++r) {
            int rowm = m0 + wm*(TM/2) + i*16 + g*4 + r;
            int bb = rowm >> 11, ss = rowm & 2047;
            dst[(((size_t)(bb*NH_ + h))*S_ + ss)*HD_ + d] = f2bf(acc[i][j][r] + bv);
          }
      } else if (which == 1) {
        unsigned short* dst = qkv_base + (size_t)QKV_ELEMS;
        #pragma unroll
        for (int i = 0; i < NI; ++i)
          #pragma unroll
          for (int r = 0; r < 4; ++r) {
            int rowm = m0 + wm*(TM/2) + i*16 + g*4 + r;
            int bb = rowm >> 11, ss = rowm & 2047;
            size_t byteoff = ((size_t)(bb*NH_ + h)*(S_>>5) + (ss>>5))*4096
                           + (size_t)(((d>>3)*32 + (ss&31))*16 + (d&7)*2);
            dst[byteoff >> 1] = f2bf(acc[i][j][r] + bv);
          }
      } else {
        unsigned short* dst = qkv_base + 2*(size_t)QKV_ELEMS;
        #pragma unroll
        for (int i = 0; i < NI; ++i) {
          int rowm = m0 + wm*(TM/2) + i*16 + g*4;
          int bb = rowm >> 11, ss = rowm & 2047;
          unsigned w0 = (unsigned)f2bf(acc[i][j][0] + bv) | ((unsigned)f2bf(acc[i][j][1] + bv) << 16);
          unsigned w1 = (unsigned)f2bf(acc[i][j][2] + bv) | ((unsigned)f2bf(acc[i][j][3] + bv) << 16);
          uint2 u; u.x = w0; u.y = w1;
          size_t byteoff = ((size_t)(bb*NH_ + h)*(S_>>5) + (ss>>5))*4096
                         + (size_t)((((ss&31)>>3)*64 + d)*16 + (ss&7)*2);
          *reinterpret_cast<uint2*>(&dst[byteoff >> 1]) = u;
        }
      }
    } else {
      #pragma unroll
      for (int i = 0; i < NI; ++i)
        #pragma unroll
        for (int r = 0; r < 4; ++r) {
          int rowm = m0 + wm*(TM/2) + i*16 + g*4 + r;
          outp[(size_t)rowm * H_ + col] = acc[i][j][r] + bv;
        }
    }
  }
}

// ---------------- flash attention (causal), fixed-reference softmax ---------------
// R15/R19 structure; R20: __launch_bounds__(256,3) -> 3 blocks/CU resident
// (768 blocks = 256 CUs x 3, zero tail). Merged q-pair sweep; fragment-order
// 4KB tiles; wave-private 1-deep staging; fixed-ref softmax; LDS-union merge.
__global__ __launch_bounds__(256, 3)
void attn_fwd(const unsigned short* __restrict__ Qp,
              const unsigned short* __restrict__ Ktp,
              const unsigned short* __restrict__ Vtp,
              unsigned short* __restrict__ attn)
{
  __shared__ __align__(16) char smem[34816];
  float* mlb = (float*)(smem + 32768);      // [4][64] partial l (per merge pass)

  const int tid = threadIdx.x;
  const int l = tid & 63, w = tid >> 6;
  const int q31 = l & 31, hi = l >> 5;
  const int idx = blockIdx.x;
  const int bh = (idx & 7) + 8 * ((idx >> 3) % 3);
  const int pr = (idx >> 3) / 3;       // 0..31
  const unsigned short* Qh = Qp + (size_t)bh * S_ * HD_;
  const char* Ktb = (const char*)Ktp + (size_t)bh * (S_>>5) * 4096;
  const char* Vtb = (const char*)Vtp + (size_t)bh * (S_>>5) * 4096;
  const int bb = bh / NH_, hh = bh % NH_;

  unsigned short* Kl = (unsigned short*)(smem + w*8192);   // wave-uniform bases
  unsigned short* Vl = Kl + 2048;
  float* OscW = (float*)(smem + w*8192);

  const int qtH = 63 - pr, qtL = pr;
  const int qrowH = qtH*32 + q31, qrowL = qtL*32 + q31;

  bf16x8 qfH[4], qfL[4];
  #pragma unroll
  for (int ks = 0; ks < 4; ++ks) {
    qfH[ks] = *reinterpret_cast<const bf16x8*>(&Qh[(size_t)qrowH*HD_ + ks*16 + hi*8]);
    qfL[ks] = *reinterpret_cast<const bf16x8*>(&Qh[(size_t)qrowL*HD_ + ks*16 + hi*8]);
  }

  f32x16 oH0, oH1, oL0, oL1;
  #pragma unroll
  for (int r = 0; r < 16; ++r) { oH0[r]=0.f; oH1[r]=0.f; oL0[r]=0.f; oL1[r]=0.f; }
  float lrunH = 0.f, lrunL = 0.f;

  const int p = w;
  const int ntH = ((qtH - p) >> 2) + 1;
  const int ntL = (qtL >= p) ? ((qtL - p) >> 2) + 1 : 0;
  const bool dwH = ((qtH & 3) == p);
  const bool dwL = ((qtL & 3) == p);
  const int ntHm1 = ntH - 1, ntLm1 = ntL - 1;

  const char* kt = Ktb + (size_t)p*4096 + l*16;
  const char* vt = Vtb + (size_t)p*4096 + l*16;

  auto STAGE = [&]() {   // 8 async contiguous 1KB loads -> linear LDS copy
    gload_lds16(kt,        Kl);
    gload_lds16(kt + 1024, Kl + 512);
    gload_lds16(kt + 2048, Kl + 1024);
    gload_lds16(kt + 3072, Kl + 1536);
    gload_lds16(vt,        Vl);
    gload_lds16(vt + 1024, Vl + 512);
    gload_lds16(vt + 2048, Vl + 1024);
    gload_lds16(vt + 3072, Vl + 1536);
    kt += 16384; vt += 16384;
  };

  STAGE();

  for (int i = 0; i < ntH; ++i) {
    VWAIT0();                            // stage(i) landed
    bf16x8 k0 = *reinterpret_cast<const bf16x8*>(&Kl[((0+hi)*32 + q31)*8]);
    bf16x8 k1 = *reinterpret_cast<const bf16x8*>(&Kl[((2+hi)*32 + q31)*8]);
    bf16x8 k2 = *reinterpret_cast<const bf16x8*>(&Kl[((4+hi)*32 + q31)*8]);
    bf16x8 k3 = *reinterpret_cast<const bf16x8*>(&Kl[((6+hi)*32 + q31)*8]);
    bf16x8 v0 = *reinterpret_cast<const bf16x8*>(&Vl[((  hi)*64 +      q31)*8]);
    bf16x8 v1 = *reinterpret_cast<const bf16x8*>(&Vl[((2+hi)*64 +      q31)*8]);
    bf16x8 v2 = *reinterpret_cast<const bf16x8*>(&Vl[((  hi)*64 + 32 + q31)*8]);
    bf16x8 v3 = *reinterpret_cast<const bf16x8*>(&Vl[((2+hi)*64 + 32 + q31)*8]);
    LWAIT0();                            // reads done -> safe to overwrite
    if (i + 1 < ntH) STAGE();            // in flight under the whole step
    asm volatile("" ::: "memory");

    const bool doL = (i < ntL);

    f32x16 sfH;
    #pragma unroll
    for (int r = 0; r < 16; ++r) sfH[r] = 0.f;
    sfH = __builtin_amdgcn_mfma_f32_32x32x16_bf16(k0, qfH[0], sfH, 0, 0, 0);
    sfH = __builtin_amdgcn_mfma_f32_32x32x16_bf16(k1, qfH[1], sfH, 0, 0, 0);
    sfH = __builtin_amdgcn_mfma_f32_32x32x16_bf16(k2, qfH[2], sfH, 0, 0, 0);
    sfH = __builtin_amdgcn_mfma_f32_32x32x16_bf16(k3, qfH[3], sfH, 0, 0, 0);
    f32x16 sfL;
    #pragma unroll
    for (int r = 0; r < 16; ++r) sfL[r] = 0.f;
    if (doL) {
      sfL = __builtin_amdgcn_mfma_f32_32x32x16_bf16(k0, qfL[0], sfL, 0, 0, 0);
      sfL = __builtin_amdgcn_mfma_f32_32x32x16_bf16(k1, qfL[1], sfL, 0, 0, 0);
      sfL = __builtin_amdgcn_mfma_f32_32x32x16_bf16(k2, qfL[2], sfL, 0, 0, 0);
      sfL = __builtin_amdgcn_mfma_f32_32x32x16_bf16(k3, qfL[3], sfL, 0, 0, 0);
    }

    if (dwH && i == ntHm1) {
      const int kv0 = qtH*32;
      #pragma unroll
      for (int r = 0; r < 16; ++r) {
        int kv = kv0 + (r & 3) + 8*(r >> 2) + 4*hi;
        if (kv > qrowH) sfH[r] = -1e38f;
      }
    }
    if (doL && dwL && i == ntLm1) {
      const int kv0 = qtL*32;
      #pragma unroll
      for (int r = 0; r < 16; ++r) {
        int kv = kv0 + (r & 3) + 8*(r >> 2) + 4*hi;
        if (kv > qrowL) sfL[r] = -1e38f;
      }
    }

    #pragma unroll
    for (int r = 0; r < 16; ++r) sfH[r] = fexp2(sfH[r] * SCL_);
    {
      float s0 = (sfH[0]+sfH[1])+(sfH[2]+sfH[3]);
      float s1 = (sfH[4]+sfH[5])+(sfH[6]+sfH[7]);
      float s2 = (sfH[8]+sfH[9])+(sfH[10]+sfH[11]);
      float s3 = (sfH[12]+sfH[13])+(sfH[14]+sfH[15]);
      lrunH += (s0+s1)+(s2+s3);
      unsigned pw0 = cvtpk(sfH[0],sfH[1]),  pw1 = cvtpk(sfH[2],sfH[3]);
      unsigned pw2 = cvtpk(sfH[4],sfH[5]),  pw3 = cvtpk(sfH[6],sfH[7]);
      unsigned pw4 = cvtpk(sfH[8],sfH[9]),  pw5 = cvtpk(sfH[10],sfH[11]);
      unsigned pw6 = cvtpk(sfH[12],sfH[13]), pw7 = cvtpk(sfH[14],sfH[15]);
      asm("v_permlane32_swap_b32 %0, %1" : "+v"(pw0), "+v"(pw2));
      asm("v_permlane32_swap_b32 %0, %1" : "+v"(pw1), "+v"(pw3));
      asm("v_permlane32_swap_b32 %0, %1" : "+v"(pw4), "+v"(pw6));
      asm("v_permlane32_swap_b32 %0, %1" : "+v"(pw5), "+v"(pw7));
      uint4 pf0; pf0.x = pw0; pf0.y = pw1; pf0.z = pw2; pf0.w = pw3;
      uint4 pf1; pf1.x = pw4; pf1.y = pw5; pf1.z = pw6; pf1.w = pw7;
      oH0 = __builtin_amdgcn_mfma_f32_32x32x16_bf16(v0, *reinterpret_cast<bf16x8*>(&pf0), oH0, 0, 0, 0);
      oH0 = __builtin_amdgcn_mfma_f32_32x32x16_bf16(v1, *reinterpret_cast<bf16x8*>(&pf1), oH0, 0, 0, 0);
      oH1 = __builtin_amdgcn_mfma_f32_32x32x16_bf16(v2, *reinterpret_cast<bf16x8*>(&pf0), oH1, 0, 0, 0);
      oH1 = __builtin_amdgcn_mfma_f32_32x32x16_bf16(v3, *reinterpret_cast<bf16x8*>(&pf1), oH1, 0, 0, 0);
    }

    if (doL) {
      #pragma unroll
      for (int r = 0; r < 16; ++r) sfL[r] = fexp2(sfL[r] * SCL_);
      float s0 = (sfL[0]+sfL[1])+(sfL[2]+sfL[3]);
      float s1 = (sfL[4]+sfL[5])+(sfL[6]+sfL[7]);
      float s2 = (sfL[8]+sfL[9])+(sfL[10]+sfL[11]);
      float s3 = (sfL[12]+sfL[13])+(sfL[14]+sfL[15]);
      lrunL += (s0+s1)+(s2+s3);
      unsigned pw0 = cvtpk(sfL[0],sfL[1]),  pw1 = cvtpk(sfL[2],sfL[3]);
      unsigned pw2 = cvtpk(sfL[4],sfL[5]),  pw3 = cvtpk(sfL[6],sfL[7]);
      unsigned pw4 = cvtpk(sfL[8],sfL[9]),  pw5 = cvtpk(sfL[10],sfL[11]);
      unsigned pw6 = cvtpk(sfL[12],sfL[13]), pw7 = cvtpk(sfL[14],sfL[15]);
      asm("v_permlane32_swap_b32 %0, %1" : "+v"(pw0), "+v"(pw2));
      asm("v_permlane32_swap_b32 %0, %1" : "+v"(pw1), "+v"(pw3));
      asm("v_permlane32_swap_b32 %0, %1" : "+v"(pw4), "+v"(pw6));
      asm("v_permlane32_swap_b32 %0, %1" : "+v"(pw5), "+v"(pw7));
      uint4 pf0; pf0.x = pw0; pf0.y = pw1; pf0.z = pw2; pf0.w = pw3;
      uint4 pf1; pf1.x = pw4; pf1.y = pw5; pf1.z = pw6; pf1.w = pw7;
      oL0 = __builtin_amdgcn_mfma_f32_32x32x16_bf16(v0, *reinterpret_cast<bf16x8*>(&pf0), oL0, 0, 0, 0);
      oL0 = __builtin_amdgcn_mfma_f32_32x32x16_bf16(v1, *reinterpret_cast<bf16x8*>(&pf1), oL0, 0, 0, 0);
      oL1 = __builtin_amdgcn_mfma_f32_32x32x16_bf16(v2, *reinterpret_cast<bf16x8*>(&pf0), oL1, 0, 0, 0);
      oL1 = __builtin_amdgcn_mfma_f32_32x32x16_bf16(v3, *reinterpret_cast<bf16x8*>(&pf1), oL1, 0, 0, 0);
    }
  }

  const int q = tid & 31, dseg8 = tid >> 5;

  auto MERGE = [&](const f32x16& a0v, const f32x16& a1v, float lr, int qt) {
    __syncthreads();
    #pragma unroll
    for (int rr = 0; rr < 4; ++rr) {
      f32x4 a;
      #pragma unroll
      for (int e = 0; e < 4; ++e) a[e] = a0v[4*rr + e];
      *reinterpret_cast<f32x4*>(&OscW[q31*36 + 8*rr + 4*hi]) = a;
    }
    mlb[w*64 + hi*32 + q31] = lr;
    __syncthreads();
    float inv;
    {
      float lt = (mlb[q] + mlb[32+q]) + (mlb[64+q] + mlb[96+q])
               + (mlb[128+q] + mlb[160+q]) + (mlb[192+q] + mlb[224+q]);
      inv = 1.f / lt;
    }
    if (dseg8 < 4) {
      const int dd = dseg8*8;
      #define OSC(a, off) (*reinterpret_cast<f32x4*>((float*)(smem + (a)*8192) + (off)))
      f32x4 a0 = OSC(0, q*36 + dd), b0 = OSC(0, q*36 + dd + 4);
      f32x4 a1 = OSC(1, q*36 + dd), b1 = OSC(1, q*36 + dd + 4);
      f32x4 a2 = OSC(2, q*36 + dd), b2 = OSC(2, q*36 + dd + 4);
      f32x4 a3 = OSC(3, q*36 + dd), b3 = OSC(3, q*36 + dd + 4);
      f32x4 ra, rb;
      #pragma unroll
      for (int e = 0; e < 4; ++e) {
        ra[e] = ((a0[e] + a1[e]) + (a2[e] + a3[e])) * inv;
        rb[e] = ((b0[e] + b1[e]) + (b2[e] + b3[e])) * inv;
      }
      uint4 ov;
      ov.x = cvtpk(ra[0], ra[1]); ov.y = cvtpk(ra[2], ra[3]);
      ov.z = cvtpk(rb[0], rb[1]); ov.w = cvtpk(rb[2], rb[3]);
      *reinterpret_cast<uint4*>(&attn[((size_t)(bb*S_ + qt*32 + q))*H_ + hh*HD_ + dd]) = ov;
    }
    __syncthreads();
    #pragma unroll
    for (int rr = 0; rr < 4; ++rr) {
      f32x4 a;
      #pragma unroll
      for (int e = 0; e < 4; ++e) a[e] = a1v[4*rr + e];
      *reinterpret_cast<f32x4*>(&OscW[q31*36 + 8*rr + 4*hi]) = a;
    }
    __syncthreads();
    if (dseg8 >= 4) {
      const int dd = (dseg8 - 4)*8;
      f32x4 a0 = OSC(0, q*36 + dd), b0 = OSC(0, q*36 + dd + 4);
      f32x4 a1 = OSC(1, q*36 + dd), b1 = OSC(1, q*36 + dd + 4);
      f32x4 a2 = OSC(2, q*36 + dd), b2 = OSC(2, q*36 + dd + 4);
      f32x4 a3 = OSC(3, q*36 + dd), b3 = OSC(3, q*36 + dd + 4);
      #undef OSC
      f32x4 ra, rb;
      #pragma unroll
      for (int e = 0; e < 4; ++e) {
        ra[e] = ((a0[e] + a1[e]) + (a2[e] + a3[e])) * inv;
        rb[e] = ((b0[e] + b1[e]) + (b2[e] + b3[e])) * inv;
      }
      uint4 ov;
      ov.x = cvtpk(ra[0], ra[1]); ov.y = cvtpk(ra[2], ra[3]);
      ov.z = cvtpk(rb[0], rb[1]); ov.w = cvtpk(rb[2], rb[3]);
      *reinterpret_cast<uint4*>(&attn[((size_t)(bb*S_ + qt*32 + q))*H_ + hh*HD_ + 32 + dd]) = ov;
    }
    __syncthreads();
  };

  MERGE(oH0, oH1, lrunH, qtH);
  MERGE(oL0, oL1, lrunL, qtL);
}

// ---------------- launch ----------------
extern "C" void kernel_launch(void* const* d_in, const int* in_sizes, int n_in,
                              void* d_out, int out_size, void* d_ws, size_t ws_size,
                              hipStream_t stream)
{
  const float* x      = (const float*)d_in[0];
  const float* w_qkv  = (const float*)d_in[1];
  const float* b_qkv  = (const float*)d_in[2];
  const float* w_o    = (const float*)d_in[3];
  const float* b_o    = (const float*)d_in[4];
  float* out = (float*)d_out;

  unsigned short* xb    = (unsigned short*)d_ws;          // 4096x768
  unsigned short* wqkvb = xb    + (size_t)M_ * K_;        // 2304x768
  unsigned short* wob   = wqkvb + (size_t)N_QKV * K_;     // 768x768
  unsigned short* Qw    = wob   + (size_t)H_ * H_;        // Q (b,h,s,d)
  unsigned short* Ktw   = Qw + (size_t)QKV_ELEMS;         // K fragment-order tiles
  unsigned short* Vtw   = Ktw + (size_t)QKV_ELEMS;        // V fragment-order tiles
  unsigned short* attn  = Vtw + (size_t)QKV_ELEMS;        // 4096x768

  cast3<<<5376, 256, 0, stream>>>(x, xb, 786432,
                                  w_qkv, wqkvb, 442368,
                                  w_o, wob, 147456);
  gemm_nt<N_QKV, 0, 18, 128><<<576, 256, 0, stream>>>(xb, wqkvb, b_qkv, Qw, nullptr);
  attn_fwd<<<dim3(768), 256, 0, stream>>>(Qw, Ktw, Vtw, attn);
  gemm_nt<H_, 1, 6, 64><<<384, 256, 0, stream>>>(attn, wob, b_o, nullptr, out);
}

// Round 21
// 69.758 us; speedup vs baseline: 1.0410x; 1.0410x over previous
//
#include <hip/hip_runtime.h>
#include <stdint.h>

// GPT2 attention fused pipeline, MI355X/gfx950.  == R19 configuration (best) ==
// B=2, S=2048, H=768, nh=12, hd=64. fp32 I/O, bf16 internal compute (MFMA).
// R14: fragment-order 4KB K/V tiles. R15: merged q-pair sweep. R16: GEMM BK=64
// + XOR-swizzled LDS. R17: proj 64x128 tiles. R19: 1-deep attn staging,
// attn at (256,2) — (256,3) spills (R20), 2-deep staging null (R13/R17).

#define B_   2
#define S_   2048
#define H_   768
#define NH_  12
#define HD_  64
#define M_   4096      // B_*S_
#define K_   768
#define N_QKV 2304
#define QKV_ELEMS (B_*NH_*S_*HD_)   // per tensor (Q or Ktiles or Vtiles)
#define SCL_ 0.18033688f            // (1/sqrt(64)) * log2(e)

using bf16x8 = __attribute__((ext_vector_type(8))) __bf16;
using f32x4  = __attribute__((ext_vector_type(4))) float;
using f32x16 = __attribute__((ext_vector_type(16))) float;

__device__ inline unsigned short f2bf(float f) {
  unsigned int u = __float_as_uint(f);
  u = (u + 0x7FFFu + ((u >> 16) & 1u)) >> 16;   // RNE
  return (unsigned short)u;
}
__device__ inline float fexp2(float x) {        // v_exp_f32 = 2^x
  float r; asm("v_exp_f32 %0, %1" : "=v"(r) : "v"(x)); return r;
}
__device__ inline unsigned cvtpk(float lo, float hi) {
  unsigned r; asm("v_cvt_pk_bf16_f32 %0, %1, %2" : "=v"(r) : "v"(lo), "v"(hi)); return r;
}
// async global->LDS, 16B per lane; lds base wave-uniform; HW writes lane l at
// ldsbase + l*16. Fire-and-forget (R9/R10/R18 lessons).
__device__ inline void gload_lds16(const void* g, void* l) {
  __builtin_amdgcn_global_load_lds((const __attribute__((address_space(1))) void*)g,
                                   (__attribute__((address_space(3))) void*)l, 16, 0, 0);
}
#define VWAIT0() do { asm volatile("s_waitcnt vmcnt(0)" ::: "memory"); \
                      __builtin_amdgcn_sched_barrier(0); } while (0)
#define LWAIT0() do { asm volatile("s_waitcnt lgkmcnt(0)" ::: "memory"); \
                      __builtin_amdgcn_sched_barrier(0); } while (0)

// ---------------- cast fp32 -> bf16 (3 tensors in one launch) ----------------
__global__ void cast3(const float* __restrict__ s0, unsigned short* __restrict__ d0, int n0f,
                      const float* __restrict__ s1, unsigned short* __restrict__ d1, int n1f,
                      const float* __restrict__ s2, unsigned short* __restrict__ d2, int n2f) {
  int i = blockIdx.x * blockDim.x + threadIdx.x;
  const float* s; unsigned short* d; int j;
  if (i < n0f)                { s = s0; d = d0; j = i; }
  else if (i < n0f + n1f)     { s = s1; d = d1; j = i - n0f; }
  else if (i < n0f + n1f + n2f) { s = s2; d = d2; j = i - n0f - n1f; }
  else return;
  float4 v = reinterpret_cast<const float4*>(s)[j];
  ushort4 o;
  o.x = f2bf(v.x); o.y = f2bf(v.y); o.z = f2bf(v.z); o.w = f2bf(v.w);
  reinterpret_cast<ushort4*>(d)[j] = o;
}

// ---------------- NT GEMM: C[m,n] = sum_k A[m,k]*Bw[n,k] + bias[n] ----------------
// R16: BK=64 + XOR-swizzled LDS (linear dest, inverse-swizzled global source).
// R17: template TM (128 for QKV, 64 for proj -> 384 blocks).
// MODE 0 scatter: Q row-major; K/V fragment-order 4KB tiles (see R14).
// MODE 1: fp32 store to out.
template<int N, int MODE, int GX, int TM>
__global__ __launch_bounds__(256, 3)
void gemm_nt(const unsigned short* __restrict__ A,
             const unsigned short* __restrict__ Bw,
             const float* __restrict__ bias,
             unsigned short* __restrict__ qkv_base,
             float* __restrict__ outp)
{
  __shared__ unsigned short As[TM*64];
  __shared__ unsigned short Bs[128*64];
  const int tid  = threadIdx.x;
  const int lane = tid & 63;
  const int wid  = tid >> 6;
  const int g = lane >> 4, lr = lane & 15;
  const int wm = wid >> 1, wn = wid & 1;
  const int cpx = (GX * (M_/TM)) >> 3;
  const int id  = blockIdx.x;
  const int sw  = (id & 7) * cpx + (id >> 3);
  const int n0 = (sw % GX) * 128;
  const int m0 = (sw / GX) * TM;
  constexpr int NI = TM / 32;              // 16-row frags per wave (M dir)

  f32x4 acc[NI][4];
  #pragma unroll
  for (int i = 0; i < NI; ++i)
    #pragma unroll
    for (int j = 0; j < 4; ++j) acc[i][j] = f32x4{0.f, 0.f, 0.f, 0.f};

  for (int k0 = 0; k0 < K_; k0 += 64) {
    #pragma unroll
    for (int it = 0; it < TM/32; ++it) {   // A: TM*8 chunks
      int c = it*256 + wid*64 + lane;
      int row = c >> 3, seg = (c & 7) ^ (row & 7);
      int lb = __builtin_amdgcn_readfirstlane((it*256 + wid*64) * 8);
      gload_lds16(&A[(size_t)(m0 + row) * K_ + k0 + seg*8], &As[lb]);
    }
    #pragma unroll
    for (int it = 0; it < 4; ++it) {       // B: 1024 chunks
      int c = it*256 + wid*64 + lane;
      int row = c >> 3, seg = (c & 7) ^ (row & 7);
      int lb = __builtin_amdgcn_readfirstlane((it*256 + wid*64) * 8);
      gload_lds16(&Bw[(size_t)(n0 + row) * K_ + k0 + seg*8], &Bs[lb]);
    }
    __syncthreads();
    #pragma unroll
    for (int ks = 0; ks < 2; ++ks) {
      bf16x8 af[NI], bfr[4];
      #pragma unroll
      for (int i = 0; i < NI; ++i) {
        int ra = wm*(TM/2) + i*16 + lr;
        af[i]  = *reinterpret_cast<const bf16x8*>(&As[(ra*8 + ((ks*4+g) ^ (ra&7)))*8]);
      }
      #pragma unroll
      for (int j = 0; j < 4; ++j) {
        int rb = wn*64 + j*16 + lr;
        bfr[j] = *reinterpret_cast<const bf16x8*>(&Bs[(rb*8 + ((ks*4+g) ^ (rb&7)))*8]);
      }
      #pragma unroll
      for (int i = 0; i < NI; ++i)
        #pragma unroll
        for (int j = 0; j < 4; ++j)
          acc[i][j] = __builtin_amdgcn_mfma_f32_16x16x32_bf16(af[i], bfr[j], acc[i][j], 0, 0, 0);
    }
    __syncthreads();
  }

  // epilogue: C row = m0+wm*(TM/2)+i*16+g*4+r, col = n0+wn*64+j*16+lr
  #pragma unroll
  for (int j = 0; j < 4; ++j) {
    int col = n0 + wn*64 + j*16 + lr;
    float bv = bias[col];
    if constexpr (MODE == 0) {
      int which = col / 768;               // 0=Q 1=K 2=V
      int rem = col - which * 768;
      int h = rem >> 6, d = rem & 63;
      if (which == 0) {
        unsigned short* dst = qkv_base;
        #pragma unroll
        for (int i = 0; i < NI; ++i)
          #pragma unroll
          for (int r = 0; r < 4; ++r) {
            int rowm = m0 + wm*(TM/2) + i*16 + g*4 + r;
            int bb = rowm >> 11, ss = rowm & 2047;
            dst[(((size_t)(bb*NH_ + h))*S_ + ss)*HD_ + d] = f2bf(acc[i][j][r] + bv);
          }
      } else if (which == 1) {
        unsigned short* dst = qkv_base + (size_t)QKV_ELEMS;
        #pragma unroll
        for (int i = 0; i < NI; ++i)
          #pragma unroll
          for (int r = 0; r < 4; ++r) {
            int rowm = m0 + wm*(TM/2) + i*16 + g*4 + r;
            int bb = rowm >> 11, ss = rowm & 2047;
            size_t byteoff = ((size_t)(bb*NH_ + h)*(S_>>5) + (ss>>5))*4096
                           + (size_t)(((d>>3)*32 + (ss&31))*16 + (d&7)*2);
            dst[byteoff >> 1] = f2bf(acc[i][j][r] + bv);
          }
      } else {
        unsigned short* dst = qkv_base + 2*(size_t)QKV_ELEMS;
        #pragma unroll
        for (int i = 0; i < NI; ++i) {
          int rowm = m0 + wm*(TM/2) + i*16 + g*4;
          int bb = rowm >> 11, ss = rowm & 2047;
          unsigned w0 = (unsigned)f2bf(acc[i][j][0] + bv) | ((unsigned)f2bf(acc[i][j][1] + bv) << 16);
          unsigned w1 = (unsigned)f2bf(acc[i][j][2] + bv) | ((unsigned)f2bf(acc[i][j][3] + bv) << 16);
          uint2 u; u.x = w0; u.y = w1;
          size_t byteoff = ((size_t)(bb*NH_ + h)*(S_>>5) + (ss>>5))*4096
                         + (size_t)((((ss&31)>>3)*64 + d)*16 + (ss&7)*2);
          *reinterpret_cast<uint2*>(&dst[byteoff >> 1]) = u;
        }
      }
    } else {
      #pragma unroll
      for (int i = 0; i < NI; ++i)
        #pragma unroll
        for (int r = 0; r < 4; ++r) {
          int rowm = m0 + wm*(TM/2) + i*16 + g*4 + r;
          outp[(size_t)rowm * H_ + col] = acc[i][j][r] + bv;
        }
    }
  }
}

// ---------------- flash attention (causal), fixed-reference softmax ---------------
// R15/R19 structure: merged q-pair sweep; fragment-order 4KB tiles;
// wave-private 1-deep staging; fixed-ref softmax; LDS-union merge (34.8KB).
// (256,2): live state ~185 VGPR; forcing 3 blocks/CU spills (R20).
__global__ __launch_bounds__(256, 2)
void attn_fwd(const unsigned short* __restrict__ Qp,
              const unsigned short* __restrict__ Ktp,
              const unsigned short* __restrict__ Vtp,
              unsigned short* __restrict__ attn)
{
  __shared__ __align__(16) char smem[34816];
  float* mlb = (float*)(smem + 32768);      // [4][64] partial l (per merge pass)

  const int tid = threadIdx.x;
  const int l = tid & 63, w = tid >> 6;
  const int q31 = l & 31, hi = l >> 5;
  const int idx = blockIdx.x;
  const int bh = (idx & 7) + 8 * ((idx >> 3) % 3);
  const int pr = (idx >> 3) / 3;       // 0..31
  const unsigned short* Qh = Qp + (size_t)bh * S_ * HD_;
  const char* Ktb = (const char*)Ktp + (size_t)bh * (S_>>5) * 4096;
  const char* Vtb = (const char*)Vtp + (size_t)bh * (S_>>5) * 4096;
  const int bb = bh / NH_, hh = bh % NH_;

  unsigned short* Kl = (unsigned short*)(smem + w*8192);   // wave-uniform bases
  unsigned short* Vl = Kl + 2048;
  float* OscW = (float*)(smem + w*8192);

  const int qtH = 63 - pr, qtL = pr;
  const int qrowH = qtH*32 + q31, qrowL = qtL*32 + q31;

  bf16x8 qfH[4], qfL[4];
  #pragma unroll
  for (int ks = 0; ks < 4; ++ks) {
    qfH[ks] = *reinterpret_cast<const bf16x8*>(&Qh[(size_t)qrowH*HD_ + ks*16 + hi*8]);
    qfL[ks] = *reinterpret_cast<const bf16x8*>(&Qh[(size_t)qrowL*HD_ + ks*16 + hi*8]);
  }

  f32x16 oH0, oH1, oL0, oL1;
  #pragma unroll
  for (int r = 0; r < 16; ++r) { oH0[r]=0.f; oH1[r]=0.f; oL0[r]=0.f; oL1[r]=0.f; }
  float lrunH = 0.f, lrunL = 0.f;

  const int p = w;
  const int ntH = ((qtH - p) >> 2) + 1;
  const int ntL = (qtL >= p) ? ((qtL - p) >> 2) + 1 : 0;
  const bool dwH = ((qtH & 3) == p);
  const bool dwL = ((qtL & 3) == p);
  const int ntHm1 = ntH - 1, ntLm1 = ntL - 1;

  const char* kt = Ktb + (size_t)p*4096 + l*16;
  const char* vt = Vtb + (size_t)p*4096 + l*16;

  auto STAGE = [&]() {   // 8 async contiguous 1KB loads -> linear LDS copy
    gload_lds16(kt,        Kl);
    gload_lds16(kt + 1024, Kl + 512);
    gload_lds16(kt + 2048, Kl + 1024);
    gload_lds16(kt + 3072, Kl + 1536);
    gload_lds16(vt,        Vl);
    gload_lds16(vt + 1024, Vl + 512);
    gload_lds16(vt + 2048, Vl + 1024);
    gload_lds16(vt + 3072, Vl + 1536);
    kt += 16384; vt += 16384;
  };

  STAGE();

  for (int i = 0; i < ntH; ++i) {
    VWAIT0();                            // stage(i) landed
    bf16x8 k0 = *reinterpret_cast<const bf16x8*>(&Kl[((0+hi)*32 + q31)*8]);
    bf16x8 k1 = *reinterpret_cast<const bf16x8*>(&Kl[((2+hi)*32 + q31)*8]);
    bf16x8 k2 = *reinterpret_cast<const bf16x8*>(&Kl[((4+hi)*32 + q31)*8]);
    bf16x8 k3 = *reinterpret_cast<const bf16x8*>(&Kl[((6+hi)*32 + q31)*8]);
    bf16x8 v0 = *reinterpret_cast<const bf16x8*>(&Vl[((  hi)*64 +      q31)*8]);
    bf16x8 v1 = *reinterpret_cast<const bf16x8*>(&Vl[((2+hi)*64 +      q31)*8]);
    bf16x8 v2 = *reinterpret_cast<const bf16x8*>(&Vl[((  hi)*64 + 32 + q31)*8]);
    bf16x8 v3 = *reinterpret_cast<const bf16x8*>(&Vl[((2+hi)*64 + 32 + q31)*8]);
    LWAIT0();                            // reads done -> safe to overwrite
    if (i + 1 < ntH) STAGE();            // in flight under the whole step
    asm volatile("" ::: "memory");

    const bool doL = (i < ntL);

    f32x16 sfH;
    #pragma unroll
    for (int r = 0; r < 16; ++r) sfH[r] = 0.f;
    sfH = __builtin_amdgcn_mfma_f32_32x32x16_bf16(k0, qfH[0], sfH, 0, 0, 0);
    sfH = __builtin_amdgcn_mfma_f32_32x32x16_bf16(k1, qfH[1], sfH, 0, 0, 0);
    sfH = __builtin_amdgcn_mfma_f32_32x32x16_bf16(k2, qfH[2], sfH, 0, 0, 0);
    sfH = __builtin_amdgcn_mfma_f32_32x32x16_bf16(k3, qfH[3], sfH, 0, 0, 0);
    f32x16 sfL;
    #pragma unroll
    for (int r = 0; r < 16; ++r) sfL[r] = 0.f;
    if (doL) {
      sfL = __builtin_amdgcn_mfma_f32_32x32x16_bf16(k0, qfL[0], sfL, 0, 0, 0);
      sfL = __builtin_amdgcn_mfma_f32_32x32x16_bf16(k1, qfL[1], sfL, 0, 0, 0);
      sfL = __builtin_amdgcn_mfma_f32_32x32x16_bf16(k2, qfL[2], sfL, 0, 0, 0);
      sfL = __builtin_amdgcn_mfma_f32_32x32x16_bf16(k3, qfL[3], sfL, 0, 0, 0);
    }

    if (dwH && i == ntHm1) {
      const int kv0 = qtH*32;
      #pragma unroll
      for (int r = 0; r < 16; ++r) {
        int kv = kv0 + (r & 3) + 8*(r >> 2) + 4*hi;
        if (kv > qrowH) sfH[r] = -1e38f;
      }
    }
    if (doL && dwL && i == ntLm1) {
      const int kv0 = qtL*32;
      #pragma unroll
      for (int r = 0; r < 16; ++r) {
        int kv = kv0 + (r & 3) + 8*(r >> 2) + 4*hi;
        if (kv > qrowL) sfL[r] = -1e38f;
      }
    }

    #pragma unroll
    for (int r = 0; r < 16; ++r) sfH[r] = fexp2(sfH[r] * SCL_);
    {
      float s0 = (sfH[0]+sfH[1])+(sfH[2]+sfH[3]);
      float s1 = (sfH[4]+sfH[5])+(sfH[6]+sfH[7]);
      float s2 = (sfH[8]+sfH[9])+(sfH[10]+sfH[11]);
      float s3 = (sfH[12]+sfH[13])+(sfH[14]+sfH[15]);
      lrunH += (s0+s1)+(s2+s3);
      unsigned pw0 = cvtpk(sfH[0],sfH[1]),  pw1 = cvtpk(sfH[2],sfH[3]);
      unsigned pw2 = cvtpk(sfH[4],sfH[5]),  pw3 = cvtpk(sfH[6],sfH[7]);
      unsigned pw4 = cvtpk(sfH[8],sfH[9]),  pw5 = cvtpk(sfH[10],sfH[11]);
      unsigned pw6 = cvtpk(sfH[12],sfH[13]), pw7 = cvtpk(sfH[14],sfH[15]);
      asm("v_permlane32_swap_b32 %0, %1" : "+v"(pw0), "+v"(pw2));
      asm("v_permlane32_swap_b32 %0, %1" : "+v"(pw1), "+v"(pw3));
      asm("v_permlane32_swap_b32 %0, %1" : "+v"(pw4), "+v"(pw6));
      asm("v_permlane32_swap_b32 %0, %1" : "+v"(pw5), "+v"(pw7));
      uint4 pf0; pf0.x = pw0; pf0.y = pw1; pf0.z = pw2; pf0.w = pw3;
      uint4 pf1; pf1.x = pw4; pf1.y = pw5; pf1.z = pw6; pf1.w = pw7;
      oH0 = __builtin_amdgcn_mfma_f32_32x32x16_bf16(v0, *reinterpret_cast<bf16x8*>(&pf0), oH0, 0, 0, 0);
      oH0 = __builtin_amdgcn_mfma_f32_32x32x16_bf16(v1, *reinterpret_cast<bf16x8*>(&pf1), oH0, 0, 0, 0);
      oH1 = __builtin_amdgcn_mfma_f32_32x32x16_bf16(v2, *reinterpret_cast<bf16x8*>(&pf0), oH1, 0, 0, 0);
      oH1 = __builtin_amdgcn_mfma_f32_32x32x16_bf16(v3, *reinterpret_cast<bf16x8*>(&pf1), oH1, 0, 0, 0);
    }

    if (doL) {
      #pragma unroll
      for (int r = 0; r < 16; ++r) sfL[r] = fexp2(sfL[r] * SCL_);
      float s0 = (sfL[0]+sfL[1])+(sfL[2]+sfL[3]);
      float s1 = (sfL[4]+sfL[5])+(sfL[6]+sfL[7]);
      float s2 = (sfL[8]+sfL[9])+(sfL[10]+sfL[11]);
      float s3 = (sfL[12]+sfL[13])+(sfL[14]+sfL[15]);
      lrunL += (s0+s1)+(s2+s3);
      unsigned pw0 = cvtpk(sfL[0],sfL[1]),  pw1 = cvtpk(sfL[2],sfL[3]);
      unsigned pw2 = cvtpk(sfL[4],sfL[5]),  pw3 = cvtpk(sfL[6],sfL[7]);
      unsigned pw4 = cvtpk(sfL[8],sfL[9]),  pw5 = cvtpk(sfL[10],sfL[11]);
      unsigned pw6 = cvtpk(sfL[12],sfL[13]), pw7 = cvtpk(sfL[14],sfL[15]);
      asm("v_permlane32_swap_b32 %0, %1" : "+v"(pw0), "+v"(pw2));
      asm("v_permlane32_swap_b32 %0, %1" : "+v"(pw1), "+v"(pw3));
      asm("v_permlane32_swap_b32 %0, %1" : "+v"(pw4), "+v"(pw6));
      asm("v_permlane32_swap_b32 %0, %1" : "+v"(pw5), "+v"(pw7));
      uint4 pf0; pf0.x = pw0; pf0.y = pw1; pf0.z = pw2; pf0.w = pw3;
      uint4 pf1; pf1.x = pw4; pf1.y = pw5; pf1.z = pw6; pf1.w = pw7;
      oL0 = __builtin_amdgcn_mfma_f32_32x32x16_bf16(v0, *reinterpret_cast<bf16x8*>(&pf0), oL0, 0, 0, 0);
      oL0 = __builtin_amdgcn_mfma_f32_32x32x16_bf16(v1, *reinterpret_cast<bf16x8*>(&pf1), oL0, 0, 0, 0);
      oL1 = __builtin_amdgcn_mfma_f32_32x32x16_bf16(v2, *reinterpret_cast<bf16x8*>(&pf0), oL1, 0, 0, 0);
      oL1 = __builtin_amdgcn_mfma_f32_32x32x16_bf16(v3, *reinterpret_cast<bf16x8*>(&pf1), oL1, 0, 0, 0);
    }
  }

  const int q = tid & 31, dseg8 = tid >> 5;

  auto MERGE = [&](const f32x16& a0v, const f32x16& a1v, float lr, int qt) {
    __syncthreads();
    #pragma unroll
    for (int rr = 0; rr < 4; ++rr) {
      f32x4 a;
      #pragma unroll
      for (int e = 0; e < 4; ++e) a[e] = a0v[4*rr + e];
      *reinterpret_cast<f32x4*>(&OscW[q31*36 + 8*rr + 4*hi]) = a;
    }
    mlb[w*64 + hi*32 + q31] = lr;
    __syncthreads();
    float inv;
    {
      float lt = (mlb[q] + mlb[32+q]) + (mlb[64+q] + mlb[96+q])
               + (mlb[128+q] + mlb[160+q]) + (mlb[192+q] + mlb[224+q]);
      inv = 1.f / lt;
    }
    if (dseg8 < 4) {
      const int dd = dseg8*8;
      #define OSC(a, off) (*reinterpret_cast<f32x4*>((float*)(smem + (a)*8192) + (off)))
      f32x4 a0 = OSC(0, q*36 + dd), b0 = OSC(0, q*36 + dd + 4);
      f32x4 a1 = OSC(1, q*36 + dd), b1 = OSC(1, q*36 + dd + 4);
      f32x4 a2 = OSC(2, q*36 + dd), b2 = OSC(2, q*36 + dd + 4);
      f32x4 a3 = OSC(3, q*36 + dd), b3 = OSC(3, q*36 + dd + 4);
      f32x4 ra, rb;
      #pragma unroll
      for (int e = 0; e < 4; ++e) {
        ra[e] = ((a0[e] + a1[e]) + (a2[e] + a3[e])) * inv;
        rb[e] = ((b0[e] + b1[e]) + (b2[e] + b3[e])) * inv;
      }
      uint4 ov;
      ov.x = cvtpk(ra[0], ra[1]); ov.y = cvtpk(ra[2], ra[3]);
      ov.z = cvtpk(rb[0], rb[1]); ov.w = cvtpk(rb[2], rb[3]);
      *reinterpret_cast<uint4*>(&attn[((size_t)(bb*S_ + qt*32 + q))*H_ + hh*HD_ + dd]) = ov;
    }
    __syncthreads();
    #pragma unroll
    for (int rr = 0; rr < 4; ++rr) {
      f32x4 a;
      #pragma unroll
      for (int e = 0; e < 4; ++e) a[e] = a1v[4*rr + e];
      *reinterpret_cast<f32x4*>(&OscW[q31*36 + 8*rr + 4*hi]) = a;
    }
    __syncthreads();
    if (dseg8 >= 4) {
      const int dd = (dseg8 - 4)*8;
      f32x4 a0 = OSC(0, q*36 + dd), b0 = OSC(0, q*36 + dd + 4);
      f32x4 a1 = OSC(1, q*36 + dd), b1 = OSC(1, q*36 + dd + 4);
      f32x4 a2 = OSC(2, q*36 + dd), b2 = OSC(2, q*36 + dd + 4);
      f32x4 a3 = OSC(3, q*36 + dd), b3 = OSC(3, q*36 + dd + 4);
      #undef OSC
      f32x4 ra, rb;
      #pragma unroll
      for (int e = 0; e < 4; ++e) {
        ra[e] = ((a0[e] + a1[e]) + (a2[e] + a3[e])) * inv;
        rb[e] = ((b0[e] + b1[e]) + (b2[e] + b3[e])) * inv;
      }
      uint4 ov;
      ov.x = cvtpk(ra[0], ra[1]); ov.y = cvtpk(ra[2], ra[3]);
      ov.z = cvtpk(rb[0], rb[1]); ov.w = cvtpk(rb[2], rb[3]);
      *reinterpret_cast<uint4*>(&attn[((size_t)(bb*S_ + qt*32 + q))*H_ + hh*HD_ + 32 + dd]) = ov;
    }
    __syncthreads();
  };

  MERGE(oH0, oH1, lrunH, qtH);
  MERGE(oL0, oL1, lrunL, qtL);
}

// ---------------- launch ----------------
extern "C" void kernel_launch(void* const* d_in, const int* in_sizes, int n_in,
                              void* d_out, int out_size, void* d_ws, size_t ws_size,
                              hipStream_t stream)
{
  const float* x      = (const float*)d_in[0];
  const float* w_qkv  = (const float*)d_in[1];
  const float* b_qkv  = (const float*)d_in[2];
  const float* w_o    = (const float*)d_in[3];
  const float* b_o    = (const float*)d_in[4];
  float* out = (float*)d_out;

  unsigned short* xb    = (unsigned short*)d_ws;          // 4096x768
  unsigned short* wqkvb = xb    + (size_t)M_ * K_;        // 2304x768
  unsigned short* wob   = wqkvb + (size_t)N_QKV * K_;     // 768x768
  unsigned short* Qw    = wob   + (size_t)H_ * H_;        // Q (b,h,s,d)
  unsigned short* Ktw   = Qw + (size_t)QKV_ELEMS;         // K fragment-order tiles
  unsigned short* Vtw   = Ktw + (size_t)QKV_ELEMS;        // V fragment-order tiles
  unsigned short* attn  = Vtw + (size_t)QKV_ELEMS;        // 4096x768

  cast3<<<5376, 256, 0, stream>>>(x, xb, 786432,
                                  w_qkv, wqkvb, 442368,
                                  w_o, wob, 147456);
  gemm_nt<N_QKV, 0, 18, 128><<<576, 256, 0, stream>>>(xb, wqkvb, b_qkv, Qw, nullptr);
  attn_fwd<<<dim3(768), 256, 0, stream>>>(Qw, Ktw, Vtw, attn);
  gemm_nt<H_, 1, 6, 64><<<384, 256, 0, stream>>>(attn, wob, b_o, nullptr, out);
}